// Round 4
// baseline (1231.390 us; speedup 1.0000x reference)
//
#include <hip/hip_runtime.h>
#include <hip/hip_fp16.h>

// Persistent 256-block kernel (1 block/CU forced by ~156 KB LDS).
// Rows 2b,2b+1 of all 64 Omega_t cached ONCE in LDS as fp16 (validated
// R4-R8, absmax 0.0078). NTAY=3 Taylor terms of expm(A)@v.
//
// Exchange (fence-free): relaxed agent-scope 8-byte atomics only.
// TWO floats per word, tag in low-2 mantissa bits of float0 (one atom ->
// no ordering needed). 256 words per round, ONE PER 64B LINE (R13's packed
// layout REGRESSED -40us: 8 publishers/line serialize at the coherence
// point; atomic loads don't coalesce -> no poller gain. Spread restored.)
// 4 rotating buffers (64 KB of d_ws, re-poisoned 0xAA each launch; poison
// low2=2 != tag 0 of rounds 0..3). Skew induction: publish r+1 strictly
// after full gather of r -> distance-4 buffer + period-16 tag reuse safe.
//
// R12 FAILED (890us): device-wide atomicAdd h1 reduction serialized at MALL.
// R13 FAILED (292us vs R11 252us): packed exchange, publisher line-contention.
// R14 (this round): ROUNDS/STEP 4 -> 3 (81 -> 61 total round-trips).
//  - wave0's T3 poll8 already gives every block the FULL vnew. The h1
//    exchange existed only because W1 columns were distributed. Now W1-top
//    lives in REGISTERS as fp16 across the block (512 thr x 128 half2 =
//    512x256), so each block computes all 256 h1 locally after T3
//    (~0.5us wave-parallel) instead of a ~2.8us device round-trip.
//  - cB[j] = b1[j] + dot(tgt, W1bot[:,j]) exchanged ONCE at startup
//    (publish {h1_step0[b], cB[b]}, gather to h1_s/cB_s) - R12's startup
//    pattern, which was correct.
//  - h1 fp16-W1 error ~3e-4 << 0.0078 fp16-Omega floor.
//  - Kept from R11/R13: wave0-solo Taylor rounds, spread exchange, deferred
//    global stores (llog), ILP'd MLP, float4 omega staging.
//  - VGPR ~240 (w1h 128 + w2r 64 + w3r 16 + locals); steady-state body
//    needs <256 -> no spill expected at 8 waves/CU.

#define NBLK 256
#define NTHR 512
#define NSTEP 20
#define NTAY 3
#define RBUF 4

typedef unsigned long long ull;

// word i (i<256) of exchange buffer buf: 64 B apart (spread layout)
#define XW(buf, i) (X + ((((buf) << 8) + (i)) << 3))

__device__ __forceinline__ void wredsum2(float& p0, float& p1) {
#pragma unroll
  for (int off = 32; off > 0; off >>= 1) {
    float t0 = __shfl_xor(p0, off, 64);
    float t1 = __shfl_xor(p1, off, 64);
    p0 += t0;
    p1 += t1;
  }
}

__device__ __forceinline__ void publish2(ull* w, float v0, float v1, unsigned int tag2) {
  unsigned int u0 = (__float_as_uint(v0) & ~3u) | tag2;
  ull x = (ull)u0 | ((ull)__float_as_uint(v1) << 32);
  __hip_atomic_store(w, x, __ATOMIC_RELAXED, __HIP_MEMORY_SCOPE_AGENT);
}

__device__ __forceinline__ float2 poll2(ull* w, unsigned int tag2) {
  int it = 0;
  for (;;) {
    ull x = __hip_atomic_load(w, __ATOMIC_RELAXED, __HIP_MEMORY_SCOPE_AGENT);
    if ((unsigned int)(x & 3u) == tag2) {
      float2 r;
      r.x = __uint_as_float((unsigned int)x);
      r.y = __uint_as_float((unsigned int)(x >> 32));
      return r;
    }
    if (it == 0)      __builtin_amdgcn_s_sleep(1);
    else if (it == 1) __builtin_amdgcn_s_sleep(2);
    else              __builtin_amdgcn_s_sleep(4);
    if (it < 2) ++it;
  }
}

// lane-quad poll: 4 words (64 B apart) -> 8 floats; all 4 loads kept in
// flight per retry iteration (hand-unrolled, no runtime-indexed arrays).
__device__ __forceinline__ void poll8(ull* w0, unsigned int tg, float* o) {
  ull x0 = 0, x1 = 0, x2 = 0, x3 = 0;
  bool g0 = false, g1 = false, g2 = false, g3 = false;
  int it = 0;
  for (;;) {
    if (!g0) { ull x = __hip_atomic_load(w0,      __ATOMIC_RELAXED, __HIP_MEMORY_SCOPE_AGENT); if ((unsigned int)(x & 3u) == tg) { x0 = x; g0 = true; } }
    if (!g1) { ull x = __hip_atomic_load(w0 + 8,  __ATOMIC_RELAXED, __HIP_MEMORY_SCOPE_AGENT); if ((unsigned int)(x & 3u) == tg) { x1 = x; g1 = true; } }
    if (!g2) { ull x = __hip_atomic_load(w0 + 16, __ATOMIC_RELAXED, __HIP_MEMORY_SCOPE_AGENT); if ((unsigned int)(x & 3u) == tg) { x2 = x; g2 = true; } }
    if (!g3) { ull x = __hip_atomic_load(w0 + 24, __ATOMIC_RELAXED, __HIP_MEMORY_SCOPE_AGENT); if ((unsigned int)(x & 3u) == tg) { x3 = x; g3 = true; } }
    if (g0 && g1 && g2 && g3) break;
    if (it == 0)      __builtin_amdgcn_s_sleep(1);
    else if (it == 1) __builtin_amdgcn_s_sleep(2);
    else              __builtin_amdgcn_s_sleep(4);
    if (it < 2) ++it;
  }
  o[0] = __uint_as_float((unsigned int)x0); o[1] = __uint_as_float((unsigned int)(x0 >> 32));
  o[2] = __uint_as_float((unsigned int)x1); o[3] = __uint_as_float((unsigned int)(x1 >> 32));
  o[4] = __uint_as_float((unsigned int)x2); o[5] = __uint_as_float((unsigned int)(x2 >> 32));
  o[6] = __uint_as_float((unsigned int)x3); o[7] = __uint_as_float((unsigned int)(x3 >> 32));
}

__global__ __launch_bounds__(NTHR, 2) void petri_kernel(
    const float* __restrict__ vsrc, const float* __restrict__ vtgt,
    const float* __restrict__ omg,  const float* __restrict__ W1,
    const float* __restrict__ b1,   const float* __restrict__ W2,
    const float* __restrict__ b2,   const float* __restrict__ W3,
    const float* __restrict__ b3,   const float* __restrict__ gum,
    ull* __restrict__ X, float* __restrict__ out) {
  __shared__ __half2 oh[64 * 512];   // 128 KB: {row2b[j], row2b+1[j]} per t
  __shared__ __align__(16) float A0_s[512];
  __shared__ __align__(16) float A1_s[512];
  __shared__ __align__(16) float v_loc[512];
  __shared__ float tgt_s[512];
  __shared__ float w1c_s[1024];      // W1 column b (both halves; startup only)
  __shared__ float cB_s[256];        // cB[j] (gathered at startup)
  __shared__ float gum_s[NSTEP * 64];
  __shared__ float b2_s[128], b3_s[64];
  __shared__ float soft_s[64], h1_s[256], h2_s[128];
  __shared__ float redp[512];
  __shared__ float llog[NSTEP * 64]; // deferred logits
  __shared__ float rf8[8], rf8b[8];
  __shared__ int   ri8[8];
  __shared__ int   bc[1];

  const int b = blockIdx.x, tid = threadIdx.x;
  const int wv = tid >> 6, ln = tid & 63;

  v_loc[tid] = vsrc[tid];
  tgt_s[tid] = vtgt[tid];
  w1c_s[tid] = W1[tid * 256 + b];
  w1c_s[tid + 512] = W1[(tid + 512) * 256 + b];
  for (int i = tid; i < NSTEP * 64; i += NTHR) gum_s[i] = gum[i];
  if (tid >= NTHR - 128) {
    int j = tid - (NTHR - 128);
    b2_s[j] = b2[j];
    if (j < 64) b3_s[j] = b3[j];
  }
  // W2 column slice in registers: thread (o=tid&127,q=tid>>7) holds
  // W2[(q*64+i)*128+o], i=0..63
  float w2r[64];
  {
    const int o = tid & 127, q = tid >> 7;
    const float* p = W2 + ((q << 6) * 128) + o;
#pragma unroll
    for (int i = 0; i < 64; ++i) w2r[i] = p[i * 128];
  }
  // W3 slice: thread (o=tid&63,q=tid>>6) holds W3[(q*16+i)*64+o], i=0..15
  float w3r[16];
  {
    const int o = tid & 63, q = tid >> 6;
    const float* p = W3 + ((q << 4) * 64) + o;
#pragma unroll
    for (int i = 0; i < 16; ++i) w3r[i] = p[i * 64];
  }
  // R14: W1-top slice in fp16 registers. Thread (j=tid&255, hf=tid>>8)
  // holds W1[(hf*256 + 2i, 2i+1) * 256 + j] packed in w1h[i], i=0..127.
  // 64-lane-consecutive j -> each load instr covers 256B contiguous.
  __half2 w1h[128];
  {
    const int j = tid & 255, hf = tid >> 8;
    const float* wp = W1 + ((hf << 8) * 256) + j;
#pragma unroll
    for (int i = 0; i < 128; ++i) {
      const float a = wp[((i << 1)) * 256];
      const float c = wp[((i << 1) + 1) * 256];
      w1h[i] = __floats2half2_rn(a, c);
    }
  }
  // Omega rows 2b,2b+1 -> LDS fp16, float4-vectorized
  {
    const int tq = tid >> 7;            // 0..3 : t within group of 4
    const int c4 = (tid & 127) << 2;    // col 0..508 step 4
    const float* rp = omg + (b << 10) + c4;
#pragma unroll 4
    for (int g = 0; g < 16; ++g) {
      const int t = (g << 2) + tq;
      const float* p = rp + t * 262144;
      const float4 f0 = *(const float4*)(p);        // row 2b
      const float4 f1 = *(const float4*)(p + 512);  // row 2b+1
      __half2* dst = oh + t * 512 + c4;
      dst[0] = __floats2half2_rn(f0.x, f1.x);
      dst[1] = __floats2half2_rn(f0.y, f1.y);
      dst[2] = __floats2half2_rn(f0.z, f1.z);
      dst[3] = __floats2half2_rn(f0.w, f1.w);
    }
  }
  __syncthreads();

  // startup round 0: publish {h1_step0[b], cB[b]}; gather both vectors.
  {
    float p0 = tgt_s[tid] * w1c_s[tid + 512];   // -> cB
    float p1 = v_loc[tid] * w1c_s[tid];         // -> h1 of step 0
    wredsum2(p0, p1);
    if (ln == 0) { rf8[wv] = p0; rf8b[wv] = p1; }
    __syncthreads();
    if (tid == 0) {
      float cB = b1[b], dv = 0.f;
      for (int q = 0; q < 8; ++q) { cB += rf8[q]; dv += rf8b[q]; }
      publish2(XW(0, b), fmaxf(dv + cB, 0.f), cB, 0u);
    }
    if (tid < 256) {
      float2 g = poll2(XW(0, tid), 0u);
      h1_s[tid] = g.x;
      cB_s[tid] = g.y;
    }
    __syncthreads();
  }

  // target argmax (identical in every block), first-index tie-break
  int tgtIdx;
  {
    float v = tgt_s[tid]; int ix = tid;
#pragma unroll
    for (int off = 32; off > 0; off >>= 1) {
      float ov = __shfl_xor(v, off, 64); int oi = __shfl_xor(ix, off, 64);
      if (ov > v || (ov == v && oi < ix)) { v = ov; ix = oi; }
    }
    if (ln == 0) { rf8[wv] = v; ri8[wv] = ix; }
    __syncthreads();
    if (tid == 0) {
      float bv = rf8[0]; int bix = ri8[0];
      for (int q = 1; q < 8; ++q)
        if (rf8[q] > bv || (rf8[q] == bv && ri8[q] < bix)) { bv = rf8[q]; bix = ri8[q]; }
      bc[0] = bix;
    }
    __syncthreads();
    tgtIdx = bc[0];
    __syncthreads();
  }

  int d = 0;
  int nAct = 0;  // number of active steps (uniform across blocks/threads)
  int r = 1;     // round counter; round 0 was startup. Step s: T1..T3 = 3s+1..3s+3.

  for (int s = 0; s < NSTEP; ++s) {
    if (d) continue;  // frozen (uniform across blocks); epilogue zero-fills
    nAct = s + 1;

    // ---- replicated L2/L3/softmax from h1_s (register weights) ----
    {
      const int q = tid >> 7;
      const float* hp = h1_s + (q << 6);
      float a0 = 0.f, a1 = 0.f, a2 = 0.f, a3 = 0.f;
#pragma unroll
      for (int i = 0; i < 64; i += 4) {
        a0 = fmaf(hp[i],     w2r[i],     a0);
        a1 = fmaf(hp[i + 1], w2r[i + 1], a1);
        a2 = fmaf(hp[i + 2], w2r[i + 2], a2);
        a3 = fmaf(hp[i + 3], w2r[i + 3], a3);
      }
      redp[tid] = (a0 + a1) + (a2 + a3);
    }
    __syncthreads();
    if (tid < 128) {
      float rr = redp[tid] + redp[tid + 128] + redp[tid + 256] + redp[tid + 384] + b2_s[tid];
      h2_s[tid] = fmaxf(rr, 0.f);
    }
    __syncthreads();
    {
      const int q = tid >> 6;
      const float* hp = h2_s + (q << 4);
      float a0 = 0.f, a1 = 0.f;
#pragma unroll
      for (int i = 0; i < 16; i += 2) {
        a0 = fmaf(hp[i],     w3r[i],     a0);
        a1 = fmaf(hp[i + 1], w3r[i + 1], a1);
      }
      redp[tid] = a0 + a1;
    }
    __syncthreads();
    if (tid < 64) {
      float a = b3_s[tid];
#pragma unroll
      for (int q = 0; q < 8; ++q) a += redp[tid + (q << 6)];
      float lg = a + gum_s[s * 64 + tid];  // TAU = 1
      float mx = lg;
#pragma unroll
      for (int off = 32; off > 0; off >>= 1) mx = fmaxf(mx, __shfl_xor(mx, off, 64));
      float e = __expf(lg - mx);
      float sm = e;
#pragma unroll
      for (int off = 32; off > 0; off >>= 1) sm += __shfl_xor(sm, off, 64);
      soft_s[tid] = e / sm;
      llog[s * 64 + tid] = a;  // deferred logits
    }
    __syncthreads();

    // ---- mix 2 rows of A from LDS fp16 ----
    {
      float a0 = 0.f, a1 = 0.f, c0 = 0.f, c1 = 0.f;
#pragma unroll 8
      for (int t = 0; t < 64; t += 2) {
        float2 xy0 = __half22float2(oh[t * 512 + tid]);
        float2 xy1 = __half22float2(oh[(t + 1) * 512 + tid]);
        float s0 = soft_s[t], s1 = soft_s[t + 1];
        a0 = fmaf(s0, xy0.x, a0);
        c0 = fmaf(s0, xy0.y, c0);
        a1 = fmaf(s1, xy1.x, a1);
        c1 = fmaf(s1, xy1.y, c1);
      }
      A0_s[tid] = a0 + a1;
      A1_s[tid] = c0 + c1;
    }
    __syncthreads();

    // ---- rounds r..r+2: Taylor n=1..NTAY, wave0 solo, barrier-free ----
    if (wv == 0) {
      const int l8 = ln << 3;
      const float4 a00 = *(const float4*)(A0_s + l8);      // A row 2b
      const float4 a01 = *(const float4*)(A0_s + l8 + 4);
      const float4 a10 = *(const float4*)(A1_s + l8);      // A row 2b+1
      const float4 a11 = *(const float4*)(A1_s + l8 + 4);
      const float vb0 = v_loc[b << 1], vb1 = v_loc[(b << 1) + 1];
      float wreg[8];
      {
        const float4 v0 = *(const float4*)(v_loc + l8);
        const float4 v1 = *(const float4*)(v_loc + l8 + 4);
        wreg[0] = v0.x; wreg[1] = v0.y; wreg[2] = v0.z; wreg[3] = v0.w;
        wreg[4] = v1.x; wreg[5] = v1.y; wreg[6] = v1.z; wreg[7] = v1.w;
      }
      float acc0 = 0.f, acc1 = 0.f;
#pragma unroll
      for (int n = 1; n <= NTAY; ++n) {
        const int rr = r + (n - 1);
        const int buf = rr & (RBUF - 1);
        const unsigned int tg = (unsigned int)((rr >> 2) & 3);
        float p0 = 0.f, p1 = 0.f;
        p0 = fmaf(a00.x, wreg[0], p0); p0 = fmaf(a00.y, wreg[1], p0);
        p0 = fmaf(a00.z, wreg[2], p0); p0 = fmaf(a00.w, wreg[3], p0);
        p0 = fmaf(a01.x, wreg[4], p0); p0 = fmaf(a01.y, wreg[5], p0);
        p0 = fmaf(a01.z, wreg[6], p0); p0 = fmaf(a01.w, wreg[7], p0);
        p1 = fmaf(a10.x, wreg[0], p1); p1 = fmaf(a10.y, wreg[1], p1);
        p1 = fmaf(a10.z, wreg[2], p1); p1 = fmaf(a10.w, wreg[3], p1);
        p1 = fmaf(a11.x, wreg[4], p1); p1 = fmaf(a11.y, wreg[5], p1);
        p1 = fmaf(a11.z, wreg[6], p1); p1 = fmaf(a11.w, wreg[7], p1);
        wredsum2(p0, p1);
        if (ln == 0) {
          float s0, s1;
          if (n == 1) {
            s0 = p0; s1 = p1;
            acc0 = vb0 + s0; acc1 = vb1 + s1;
          } else {
            const float inv = (n == 2) ? 0.5f : (1.0f / 3.0f);
            s0 = p0 * inv; s1 = p1 * inv;
            acc0 += s0; acc1 += s1;
          }
          const float q0 = (n < NTAY) ? s0 : acc0;  // last round: vnew
          const float q1 = (n < NTAY) ? s1 : acc1;
          publish2(XW(buf, b), q0, q1, tg);
        }
        poll8(XW(buf, (ln << 2)), tg, wreg);
      }
      // vnew -> LDS; solo argmax; done flag
      *(float4*)(v_loc + l8)     = make_float4(wreg[0], wreg[1], wreg[2], wreg[3]);
      *(float4*)(v_loc + l8 + 4) = make_float4(wreg[4], wreg[5], wreg[6], wreg[7]);
      float mv = wreg[0]; int mi = l8;
#pragma unroll
      for (int k = 1; k < 8; ++k) if (wreg[k] > mv) { mv = wreg[k]; mi = l8 + k; }
#pragma unroll
      for (int off = 32; off > 0; off >>= 1) {
        float ov = __shfl_xor(mv, off, 64); int oi = __shfl_xor(mi, off, 64);
        if (ov > mv || (ov == mv && oi < mi)) { mv = ov; mi = oi; }
      }
      if (ln == 0) bc[0] = (mi == tgtIdx) ? 1 : 0;
    }
    __syncthreads();
    if (bc[0]) {
      d = 1;
    } else if (s + 1 < NSTEP) {
      // ---- R14: local h1 for step s+1 from register W1 (no exchange) ----
      // Thread (j=tid&255, hf=tid>>8): partial over v[hf*256 .. +255].
      const int hf = tid >> 8;
      const float4* vp4 = (const float4*)(v_loc + (hf << 8));
      float acA = 0.f, acB = 0.f, acC = 0.f, acD = 0.f;
#pragma unroll
      for (int i = 0; i < 64; ++i) {
        const float4 v4 = vp4[i];                      // broadcast read
        const float2 wa = __half22float2(w1h[2 * i]);
        const float2 wb = __half22float2(w1h[2 * i + 1]);
        acA = fmaf(wa.x, v4.x, acA);
        acB = fmaf(wa.y, v4.y, acB);
        acC = fmaf(wb.x, v4.z, acC);
        acD = fmaf(wb.y, v4.w, acD);
      }
      redp[tid] = (acA + acB) + (acC + acD);
      __syncthreads();
      if (tid < 256)
        h1_s[tid] = fmaxf(redp[tid] + redp[tid + 256] + cB_s[tid], 0.f);
      __syncthreads();
    }
    r += NTAY;
  }

  // ---- epilogue: all global writes (block 0 only) ----
  if (b == 0) {
    out[tid] = v_loc[tid];
    for (int i = tid; i < NSTEP * 64; i += NTHR)
      out[512 + i] = (i < nAct * 64) ? llog[i] : 0.0f;
  }
}

extern "C" void kernel_launch(void* const* d_in, const int* in_sizes, int n_in,
                              void* d_out, int out_size, void* d_ws, size_t ws_size,
                              hipStream_t stream) {
  (void)in_sizes; (void)n_in; (void)out_size; (void)ws_size;
  petri_kernel<<<dim3(NBLK), dim3(NTHR), 0, stream>>>(
      (const float*)d_in[0], (const float*)d_in[1], (const float*)d_in[2],
      (const float*)d_in[3], (const float*)d_in[4], (const float*)d_in[5],
      (const float*)d_in[6], (const float*)d_in[7], (const float*)d_in[8],
      (const float*)d_in[9], (ull*)d_ws, (float*)d_out);
}